// Round 6
// baseline (156.693 us; speedup 1.0000x reference)
//
#include <hip/hip_runtime.h>

// out[b][o] = sum_d W[labels[b]][o][d] * vad[b][d]
// B=131072, OUT_DIM=768, IN_DIM=3, NUM_CLASSES=10, fp32.
// Discriminating experiment: LOAD-FREE inner loop. All 10 classes' W-slice
// for this thread's quad preloaded into registers (30 f32x4 = 120 VGPR);
// inner loop = scalar label/vad load -> uniform 10-way scalar branch ->
// 12 VALU -> one 1KB wave-store. Closest legal approximation of fillBuffer.

typedef float f32x4 __attribute__((ext_vector_type(4)));

#define B_TOTAL 131072
#define OUT_DIM 768
#define NCLS 10
#define GRID 2048
#define BLOCK 192                              // 3 waves; wave k owns quad lane+64k
#define SAMPLES_PER_BLOCK (B_TOTAL / GRID)     // 64

__global__ __launch_bounds__(BLOCK) void vad_proj_kernel(
    const float* __restrict__ vad,     // (B, 3)
    const int*   __restrict__ labels,  // (B,)
    const float* __restrict__ W,       // (10, 768, 3) row-major [l][o][d]
    float*       __restrict__ out)     // (B, 768)
{
    const int lane = threadIdx.x & 63;
    const int wv   = __builtin_amdgcn_readfirstlane((int)(threadIdx.x >> 6)); // 0..2
    const int q    = lane + (wv << 6);         // this thread's quad 0..191

    // Preload W rows 4q..4q+3 for ALL 10 classes: 30 x f32x4, stays in VGPRs
    // (every later access uses compile-time indices inside the switch cases).
    f32x4 w[NCLS][3];
    #pragma unroll
    for (int c = 0; c < NCLS; ++c) {
        const f32x4* wp = (const f32x4*)(W + (size_t)c * (OUT_DIM * 3)) + q * 3;
        w[c][0] = wp[0]; w[c][1] = wp[1]; w[c][2] = wp[2];
    }

    for (int j = 0; j < SAMPLES_PER_BLOCK; ++j) {
        const int b = blockIdx.x + j * GRID;   // lockstep: contiguous 6MB window/step
        const int l = labels[b];               // uniform -> s_load, SGPR
        const float* vb = vad + (size_t)b * 3;
        const float v0 = vb[0], v1 = vb[1], v2 = vb[2];  // uniform -> s_load

        f32x4 o;
        switch (l) {                           // uniform -> scalar branch tree
#define CASE(c) case c: { \
            const f32x4 a0 = w[c][0], a1 = w[c][1], a2 = w[c][2]; \
            o.x = a0.x*v0 + a0.y*v1 + a0.z*v2; \
            o.y = a0.w*v0 + a1.x*v1 + a1.y*v2; \
            o.z = a1.z*v0 + a1.w*v1 + a2.x*v2; \
            o.w = a2.y*v0 + a2.z*v1 + a2.w*v2; } break;
            CASE(0) CASE(1) CASE(2) CASE(3) CASE(4)
            CASE(5) CASE(6) CASE(7) CASE(8) CASE(9)
#undef CASE
            default: o = (f32x4)(0.0f); break;
        }

        // block's 192 threads write one full sample: 3KB contiguous
        ((f32x4*)(out + (size_t)b * OUT_DIM))[q] = o;
    }
}

extern "C" void kernel_launch(void* const* d_in, const int* in_sizes, int n_in,
                              void* d_out, int out_size, void* d_ws, size_t ws_size,
                              hipStream_t stream) {
    const float* vad    = (const float*)d_in[0];
    const int*   labels = (const int*)d_in[1];
    const float* W      = (const float*)d_in[2];
    float*       out    = (float*)d_out;

    vad_proj_kernel<<<GRID, BLOCK, 0, stream>>>(vad, labels, W, out);
}

// Round 7
// 85.090 us; speedup vs baseline: 1.8415x; 1.8415x over previous
//
#include <hip/hip_runtime.h>

// out[b][o] = sum_d W[labels[b]][o][d] * vad[b][d]
// B=131072, OUT_DIM=768, IN_DIM=3, NUM_CLASSES=10, fp32.
// Discriminator: remove ALL scalar-memory (s_load) traffic from the sample
// loop. Wave owns 16 CONSECUTIVE samples; labels/vad gathered via one
// coalesced VECTOR load each (L1 path, many MSHRs), broadcast per sample
// with compile-time v_readlane. Inner loop = W loads + FMA + stores only,
// independent across the 16 unrolled samples -> deep pipelining.
// Bonus: each wave writes a 48KB dense run.

typedef float f32x4 __attribute__((ext_vector_type(4)));

#define B_TOTAL 131072
#define OUT_DIM 768
#define SPW 16                 // consecutive samples per wave
#define BLOCK 256
#define GRID 2048              // 8192 waves x 16 samples = 131072

__global__ __launch_bounds__(BLOCK) void vad_proj_kernel(
    const float* __restrict__ vad,     // (B, 3)
    const int*   __restrict__ labels,  // (B,)
    const float* __restrict__ W,       // (10, 768, 3) row-major [l][o][d]
    float*       __restrict__ out)     // (B, 768)
{
    const int lane = threadIdx.x & 63;
    const int wave = __builtin_amdgcn_readfirstlane((int)(threadIdx.x >> 6));
    const size_t b0 = ((size_t)blockIdx.x * (BLOCK / 64) + wave) * SPW;

    // Vector-path gather: 16 labels (64B) + 48 vad floats (192B), coalesced.
    int   vlab = 0;
    float vvad = 0.0f;
    if (lane < SPW)      vlab = labels[b0 + lane];
    if (lane < 3 * SPW)  vvad = vad[b0 * 3 + lane];

    #pragma unroll
    for (int j = 0; j < SPW; ++j) {
        // compile-time lane indices -> v_readlane_b32 into SGPRs, no memory op
        const int   l  = __builtin_amdgcn_readlane(vlab, j);
        const float v0 = __int_as_float(__builtin_amdgcn_readlane(__float_as_int(vvad), 3 * j + 0));
        const float v1 = __int_as_float(__builtin_amdgcn_readlane(__float_as_int(vvad), 3 * j + 1));
        const float v2 = __int_as_float(__builtin_amdgcn_readlane(__float_as_int(vvad), 3 * j + 2));

        const f32x4* wp = (const f32x4*)(W + (size_t)l * (OUT_DIM * 3));
        f32x4* ob = (f32x4*)(out + (b0 + j) * OUT_DIM);

        #pragma unroll
        for (int k = 0; k < 3; ++k) {
            const int q = lane + 64 * k;               // quad index 0..191
            const f32x4 w0 = wp[q * 3 + 0];            // 48B/lane, L1/L2-hot
            const f32x4 w1 = wp[q * 3 + 1];
            const f32x4 w2 = wp[q * 3 + 2];
            f32x4 o;
            o.x = w0.x * v0 + w0.y * v1 + w0.z * v2;
            o.y = w0.w * v0 + w1.x * v1 + w1.y * v2;
            o.z = w1.z * v0 + w1.w * v1 + w2.x * v2;
            o.w = w2.y * v0 + w2.z * v1 + w2.w * v2;
            ob[q] = o;                                 // 1KB wave-store, dense run
        }
    }
}

extern "C" void kernel_launch(void* const* d_in, const int* in_sizes, int n_in,
                              void* d_out, int out_size, void* d_ws, size_t ws_size,
                              hipStream_t stream) {
    const float* vad    = (const float*)d_in[0];
    const int*   labels = (const int*)d_in[1];
    const float* W      = (const float*)d_in[2];
    float*       out    = (float*)d_out;

    vad_proj_kernel<<<GRID, BLOCK, 0, stream>>>(vad, labels, W, out);
}